// Round 3
// baseline (1908.844 us; speedup 1.0000x reference)
//
#include <hip/hip_runtime.h>
#include <hip/hip_bf16.h>
#include <math.h>

// Shapes (fixed): B=8, L=512, D=768, H=12, DK=64, N=B*L=4096, BH=96
// Output layout (floats): context[37748736] | d[25165824] | d0[49152] | loss[1]
// Scratch plan: Q,K, LL(Mv), Mp, Inv live inside the context output region.
// After scores_kernel, the Qs/Ks region is reused for packed-x (xh|xl, u32
// pair-format) = ctx rows of bh 0..7; context is computed in two launches:
// packed MFMA kernel for bh 8..95 (reads xh/xl), then the R1 fallback kernel
// for bh 0..7 (reads raw x; its ctx writes overwrite xh/xl only after the
// packed kernel finished, by stream order).
//
// R2 changes:
//  (1) gj_inv: per-pivot shuffles batched into rj[64] gather then update
//      (forces ILP; math bitwise-identical to R1's version).
//  (2) pack_x_kernel: x -> xh/xl (RNE hi-pair, trunc residual-pair).
//  (3) context_packed_kernel: B staging = pure copy; A staging = 3-op trunc
//      pair-pack; LDS [k2][132] with b128 conflict-free writes; no frag perms.

#define INV_SQRT_D 0.03608439182435161f  // 1/sqrt(768)

typedef short bf16x8 __attribute__((ext_vector_type(8)));
typedef float f32x4 __attribute__((ext_vector_type(4)));
typedef unsigned int u32x4 __attribute__((ext_vector_type(4)));

// ---------------------------------------------------------------------------
// 8x8-per-thread fp32 GEMM micro kernel over a K-chunk of 16.
__device__ __forceinline__ void mm_micro(const float* At, const float* Bt,
                                         float acc[8][8], int tx, int ty)
{
#pragma unroll
  for (int t = 0; t < 16; ++t) {
    const float4 a0 = *(const float4*)(At + t*132 + ty*8);
    const float4 a1 = *(const float4*)(At + t*132 + ty*8 + 4);
    const float4 b0 = *(const float4*)(Bt + t*132 + tx*8);
    const float4 b1 = *(const float4*)(Bt + t*132 + tx*8 + 4);
    const float a[8] = {a0.x,a0.y,a0.z,a0.w,a1.x,a1.y,a1.z,a1.w};
    const float b[8] = {b0.x,b0.y,b0.z,b0.w,b1.x,b1.y,b1.z,b1.w};
#pragma unroll
    for (int i = 0; i < 8; ++i)
#pragma unroll
      for (int j = 0; j < 8; ++j)
        acc[i][j] = fmaf(a[i], b[j], acc[i][j]);
  }
}

// ---------------------------------------------------------------------------
__global__ __launch_bounds__(256) void proj_kernel(
    const float* __restrict__ x,
    const float* __restrict__ Wq, const float* __restrict__ bq,
    const float* __restrict__ Wk, const float* __restrict__ bk,
    float* __restrict__ Q, float* __restrict__ Kc)
{
  const float* W; const float* bias; float* out; float scale;
  if (blockIdx.z == 0) { W = Wq; bias = bq; out = Q;  scale = INV_SQRT_D; }
  else                 { W = Wk; bias = bk; out = Kc; scale = 1.0f; }

  __shared__ __align__(16) float At[16*132];
  __shared__ __align__(16) float Bt[16*132];

  const int tx = threadIdx.x, ty = threadIdx.y;
  const int tid = ty*16 + tx;
  const int row0 = blockIdx.y * 128, col0 = blockIdx.x * 128;
  const int lt = tid & 15, lr = tid >> 4;
  const int bc = tid & 127, btr = tid >> 7;

  float acc[8][8] = {};

  for (int kk = 0; kk < 768; kk += 16) {
#pragma unroll
    for (int u = 0; u < 8; ++u) {
      const int r = lr + 16*u;
      At[lt*132 + r] = x[(size_t)(row0 + r)*768 + kk + lt];
    }
#pragma unroll
    for (int u = 0; u < 8; ++u) {
      const int t = btr + 2*u;
      Bt[t*132 + bc] = W[(size_t)(kk + t)*768 + col0 + bc];
    }
    __syncthreads();
    mm_micro(At, Bt, acc, tx, ty);
    __syncthreads();
  }

#pragma unroll
  for (int i = 0; i < 8; ++i) {
    const int r = row0 + ty*8 + i;
#pragma unroll
    for (int j = 0; j < 8; j += 4) {
      const int c = col0 + tx*8 + j;
      float4 v;
      v.x = (acc[i][j+0] + bias[c+0]) * scale;
      v.y = (acc[i][j+1] + bias[c+1]) * scale;
      v.z = (acc[i][j+2] + bias[c+2]) * scale;
      v.w = (acc[i][j+3] + bias[c+3]) * scale;
      *(float4*)(out + (size_t)r*768 + c) = v;
    }
  }
}

// ---------------------------------------------------------------------------
__global__ __launch_bounds__(256) void root_kernel(
    const float* __restrict__ x, const float* __restrict__ Wr,
    const float* __restrict__ br, const float* __restrict__ mask,
    float* __restrict__ Rv, float* __restrict__ mv)
{
  const int n = blockIdx.x*4 + (threadIdx.x >> 6);
  const int lane = threadIdx.x & 63;
  float s = 0.0f;
  for (int c = lane; c < 768; c += 64) s += x[(size_t)n*768 + c] * Wr[c];
#pragma unroll
  for (int off = 32; off > 0; off >>= 1) s += __shfl_down(s, off, 64);
  if (lane == 0) {
    const float root = s + br[0];
    const float m = mask[n] * (-1e-4f);
    Rv[n] = expf(fmaxf(root - m*50.0f, -40.0f));
    mv[n] = m;
  }
}

// ---------------------------------------------------------------------------
__global__ __launch_bounds__(256) void scores_kernel(
    const float* __restrict__ Qs, const float* __restrict__ Ks,
    const float* __restrict__ mv, float* __restrict__ A)
{
  const int bh = blockIdx.z, b = bh / 12, h = bh % 12;
  const int i0 = blockIdx.y * 128, j0 = blockIdx.x * 128;
  __shared__ __align__(16) float At[16*132];
  __shared__ __align__(16) float Bt[16*132];
  const int tx = threadIdx.x, ty = threadIdx.y;
  const int tid = ty*16 + tx;
  const int lt = tid & 15, lr = tid >> 4;
  const size_t qbase = (size_t)(b*512 + i0)*768 + h*64;
  const size_t kbase = (size_t)(b*512 + j0)*768 + h*64;

  float acc[8][8] = {};

  for (int kk = 0; kk < 64; kk += 16) {
#pragma unroll
    for (int u = 0; u < 8; ++u) {
      const int r = lr + 16*u;
      At[lt*132 + r] = Qs[qbase + (size_t)r*768 + kk + lt];
      Bt[lt*132 + r] = Ks[kbase + (size_t)r*768 + kk + lt];
    }
    __syncthreads();
    mm_micro(At, Bt, acc, tx, ty);
    __syncthreads();
  }

  float mi[8], mj[8];
#pragma unroll
  for (int i = 0; i < 8; ++i) mi[i] = mv[b*512 + i0 + ty*8 + i];
#pragma unroll
  for (int j = 0; j < 8; ++j) mj[j] = mv[b*512 + j0 + tx*8 + j];

#pragma unroll
  for (int i = 0; i < 8; ++i) {
    const size_t rowb = (size_t)(bh*512 + i0 + ty*8 + i)*512;
#pragma unroll
    for (int j = 0; j < 8; j += 4) {
      float4 v;
      v.x = expf(fmaxf(acc[i][j+0] - (mi[i]+mj[j+0])*50.0f, -40.0f));
      v.y = expf(fmaxf(acc[i][j+1] - (mi[i]+mj[j+1])*50.0f, -40.0f));
      v.z = expf(fmaxf(acc[i][j+2] - (mi[i]+mj[j+2])*50.0f, -40.0f));
      v.w = expf(fmaxf(acc[i][j+3] - (mi[i]+mj[j+3])*50.0f, -40.0f));
      *(float4*)(A + rowb + j0 + tx*8 + j) = v;
    }
  }
}

// ---------------------------------------------------------------------------
// pack_x: x -> xh (RNE-bf16 pair of rows 2k2,2k2+1) and xl (trunc residual
// pair). Layout [k2g][768] u32 with k2g = b*256 + k2, i.e. global row pair
// (2*k2g, 2*k2g+1).
__global__ __launch_bounds__(256) void pack_x_kernel(
    const float* __restrict__ x, unsigned int* __restrict__ xh,
    unsigned int* __restrict__ xl)
{
  const int gid = blockIdx.x*256 + threadIdx.x;   // 0..393215
  const int k2g = gid / 192;                      // 0..2047
  const int cc  = (gid - k2g*192) * 4;
  const unsigned int* xb = (const unsigned int*)x;
  const size_t s0 = (size_t)(2*k2g)*768 + cc;
  const uint4 r0 = *(const uint4*)(xb + s0);
  const uint4 r1 = *(const uint4*)(xb + s0 + 768);
  unsigned int hw[4], lw[4];
#pragma unroll
  for (int i = 0; i < 4; ++i) {
    const unsigned int u0 = ((const unsigned int*)&r0)[i];
    const unsigned int u1 = ((const unsigned int*)&r1)[i];
    const unsigned int h0 = (u0 + 0x7FFFu + ((u0 >> 16) & 1u)) >> 16;
    const unsigned int h1 = (u1 + 0x7FFFu + ((u1 >> 16) & 1u)) >> 16;
    hw[i] = h0 | (h1 << 16);
    const float rs0 = __uint_as_float(u0) - __uint_as_float(h0 << 16);
    const float rs1 = __uint_as_float(u1) - __uint_as_float(h1 << 16);
    lw[i] = __builtin_amdgcn_perm(__float_as_uint(rs1), __float_as_uint(rs0),
                                  0x07060302u);
  }
  const size_t o = (size_t)k2g*768 + cc;
  *(uint4*)(xh + o) = make_uint4(hw[0], hw[1], hw[2], hw[3]);
  *(uint4*)(xl + o) = make_uint4(lw[0], lw[1], lw[2], lw[3]);
}

// ---------------------------------------------------------------------------
// colsum[bh][j] = sum_i A[bh][i][j]
__global__ void colsum_kernel(const float* __restrict__ A, float* __restrict__ colsum)
{
  const int bh = blockIdx.y;
  const int j = blockIdx.x*256 + threadIdx.x;
  const float* Ab = A + (size_t)bh*262144;
  float s = 0.0f;
  for (int i = 0; i < 512; ++i) s += Ab[(size_t)i*512 + j];
  colsum[bh*512 + j] = s;
}

// ---------------------------------------------------------------------------
__global__ void buildM_kernel(const float* __restrict__ A, const float* __restrict__ colsum,
                              const float* __restrict__ Rv, float* __restrict__ M)
{
  const size_t g = ((size_t)blockIdx.x*256 + threadIdx.x)*4;
  const int bh = (int)(g >> 18);
  const int i = (int)((g >> 9) & 511);
  const int j = (int)(g & 511);
  const float4 a = *(const float4*)(A + g);
  float4 v; v.x = -a.x; v.y = -a.y; v.z = -a.z; v.w = -a.w;
  if (i >= j && i < j+4) {
    const float dadd = colsum[bh*512 + i] + Rv[(bh/12)*512 + i];
    ((float*)&v)[i - j] += dadd;
  }
  *(float4*)(M + g) = v;
}

// ---------------------------------------------------------------------------
// gj_inv: wave0 inverts A11 (64x64) in registers. R2: per pivot, gather the
// full pivot row into rj[64] FIRST (64 independent shuffles -> pipelined),
// then the update loop. Math identical to R1's version.
__global__ __launch_bounds__(256) void gj_inv_kernel(
    const float* __restrict__ M, float* __restrict__ Mp,
    float* __restrict__ Inv, int k0)
{
  const float* const Mg  = M   + (size_t)blockIdx.x * 262144;
  float* const Mpg       = Mp  + (size_t)blockIdx.x * 32768;
  float* const Ig        = Inv + (size_t)blockIdx.x * 4096;
  const int tid = threadIdx.x;

  if (tid >= 64) {
    const int t = tid - 64;
    for (int p = 0; p < 43; ++p) {
      const int idx = p*192 + t;
      if (idx < 8192) {
        const int r = idx >> 7, c = (idx & 127) * 4;
        *(float4*)(Mpg + (size_t)r*512 + c) =
            *(const float4*)(Mg + (size_t)(k0 + r)*512 + c);
      }
    }
    return;
  }

  const int lane = tid;
  float w[64];
  {
    const float* src = Mg + (size_t)(k0 + lane)*512 + k0;
#pragma unroll
    for (int q = 0; q < 16; ++q) {
      const float4 t4 = *(const float4*)(src + q*4);
      w[q*4+0]=t4.x; w[q*4+1]=t4.y; w[q*4+2]=t4.z; w[q*4+3]=t4.w;
    }
  }

  float fcur = w[0];                      // = w[kk] at loop top
#pragma unroll 1
  for (int kk = 0; kk < 64; ++kk) {
    // batch-gather pivot row (64 independent bpermutes -> ILP)
    float rj[64];
#pragma unroll
    for (int j = 0; j < 64; ++j) rj[j] = __shfl(w[j], kk);
    const float pv = __shfl(fcur, kk);    // old M[kk][kk]
    const float p  = 1.0f / pv;
    const bool isp = (lane == kk);
    const float alpha = isp ? p : -fcur * p;
    float fnext = fcur;
#pragma unroll
    for (int j = 0; j < 64; ++j) {
      const float base = isp ? 0.0f : w[j];
      float val = fmaf(alpha, rj[j], base);
      if (j == kk) val = alpha;           // uniform cond -> select
      w[j] = val;
      if (j == kk + 1) fnext = val;       // uniform cond -> select
    }
    fcur = fnext;
  }

  {
    float* dst = Ig + lane*64;
#pragma unroll
    for (int q = 0; q < 16; ++q)
      *(float4*)(dst + q*4) = make_float4(w[q*4+0], w[q*4+1], w[q*4+2], w[q*4+3]);
  }
}

// ---------------------------------------------------------------------------
__global__ __launch_bounds__(256) void gj_w_kernel(
    float* __restrict__ M, const float* __restrict__ Inv, int k0)
{
  const int bh = blockIdx.y;
  const int row0 = blockIdx.x * 128;
  float* const Mg = M + (size_t)bh*262144;
  const float* const Ig = Inv + (size_t)bh*4096;

  __shared__ __align__(16) float Ct[16*132];
  __shared__ __align__(16) float It[16*68];

  const int tx = threadIdx.x, ty = threadIdx.y;   // (16,16)
  const int tid = ty*16 + tx;
  const int lt = tid & 15, lr = tid >> 4;

  float acc[8][4] = {};

  for (int kc = 0; kc < 64; kc += 16) {
#pragma unroll
    for (int u = 0; u < 8; ++u) {
      const int r = lr + 16*u;
      Ct[lt*132 + r] = Mg[(size_t)(row0 + r)*512 + k0 + kc + lt];   // C slice
    }
    {
      const int j = tid & 63, t0 = tid >> 6;      // t0 = 0..3
#pragma unroll
      for (int u = 0; u < 4; ++u) {
        const int t = t0*4 + u;
        It[t*68 + j] = Ig[(kc + t)*64 + j];
      }
    }
    __syncthreads();
#pragma unroll
    for (int t = 0; t < 16; ++t) {
      const float4 a0 = *(const float4*)(Ct + t*132 + ty*8);
      const float4 a1 = *(const float4*)(Ct + t*132 + ty*8 + 4);
      const float4 b  = *(const float4*)(It + t*68 + tx*4);
      const float a[8] = {a0.x,a0.y,a0.z,a0.w,a1.x,a1.y,a1.z,a1.w};
      const float bb[4] = {b.x,b.y,b.z,b.w};
#pragma unroll
      for (int i = 0; i < 8; ++i)
#pragma unroll
        for (int j = 0; j < 4; ++j)
          acc[i][j] = fmaf(a[i], bb[j], acc[i][j]);
    }
    __syncthreads();
  }

#pragma unroll
  for (int i = 0; i < 8; ++i) {
    const int irow = row0 + ty*8 + i;
    float4 v;
    if (irow >= k0 && irow < k0 + 64) {
      v = *(const float4*)(Ig + (irow - k0)*64 + tx*4);   // A11inv rows
    } else {
      v = make_float4(-acc[i][0], -acc[i][1], -acc[i][2], -acc[i][3]);
    }
    *(float4*)(Mg + (size_t)irow*512 + k0 + tx*4) = v;
  }
}

// ---------------------------------------------------------------------------
__global__ __launch_bounds__(256) void gj_update_kernel(
    float* __restrict__ M, const float* __restrict__ Mp, int k0)
{
  const int bh = blockIdx.z;
  const int row0 = blockIdx.y * 128, col0 = blockIdx.x * 128;
  float* const Mg = M + (size_t)bh*262144;
  const float* const Mpg = Mp + (size_t)bh*32768;

  __shared__ __align__(16) float At[16*132];
  __shared__ __align__(16) float Bt[16*132];
  const int tx = threadIdx.x, ty = threadIdx.y;
  const int tid = ty*16 + tx;
  const int lt = tid & 15, lr = tid >> 4;
  const int bc = tid & 127, btr = tid >> 7;

  float acc[8][8] = {};

  for (int kc = 0; kc < 64; kc += 16) {
#pragma unroll
    for (int u = 0; u < 8; ++u) {
      const int r = lr + 16*u;
      At[lt*132 + r] = Mg[(size_t)(row0 + r)*512 + k0 + kc + lt];     // W slice
    }
#pragma unroll
    for (int u = 0; u < 8; ++u) {
      const int t = btr + 2*u;
      Bt[t*132 + bc] = Mpg[(size_t)(kc + t)*512 + col0 + bc];         // Mp_old
    }
    __syncthreads();
    mm_micro(At, Bt, acc, tx, ty);
    __syncthreads();
  }

#pragma unroll
  for (int ii = 0; ii < 8; ++ii) {
    const int irow = row0 + ty*8 + ii;
    const bool inP = (irow >= k0) && (irow < k0 + 64);
#pragma unroll
    for (int jj = 0; jj < 8; jj += 4) {
      const int jcol = col0 + tx*8 + jj;
      if (jcol >= k0 && jcol < k0 + 64) continue;   // panel cols hold W
      float* cell = Mg + (size_t)irow*512 + jcol;
      float4 v = make_float4(acc[ii][jj+0], acc[ii][jj+1], acc[ii][jj+2], acc[ii][jj+3]);
      if (!inP) {
        const float4 o = *(const float4*)cell;
        v.x += o.x; v.y += o.y; v.z += o.z; v.w += o.w;
      }
      *(float4*)cell = v;
    }
  }
}

// ---------------------------------------------------------------------------
__global__ void diag_d0_kernel(const float* __restrict__ Minv, const float* __restrict__ Rv,
                               float* __restrict__ diagv, float* __restrict__ d0)
{
  const int bh = blockIdx.x, l = threadIdx.x;
  const float dg = Minv[(size_t)bh*262144 + (size_t)l*513];
  diagv[bh*512 + l] = dg;
  d0[bh*512 + l] = Rv[(bh/12)*512 + l] * dg;
}

// ---------------------------------------------------------------------------
__global__ __launch_bounds__(1024) void loss_kernel(const float* __restrict__ d0,
                                                    const int* __restrict__ labels,
                                                    float* __restrict__ loss)
{
  float acc = 0.0f;
  for (int n = threadIdx.x; n < 4096; n += 1024) {
    if (labels[n] != 0) {
      const int b = n >> 9, l = n & 511;
      float s = 0.0f;
#pragma unroll
      for (int h = 0; h < 12; ++h) {
        float p = d0[(size_t)(b*12 + h)*512 + l];
        p = fminf(fmaxf(p, 1e-5f), 1.0f - 1e-5f);
        s -= logf(p);
      }
      acc += s;
    }
  }
  __shared__ float red[16];
#pragma unroll
  for (int off = 32; off > 0; off >>= 1) acc += __shfl_down(acc, off, 64);
  const int wv = threadIdx.x >> 6, ln = threadIdx.x & 63;
  if (ln == 0) red[wv] = acc;
  __syncthreads();
  if (threadIdx.x == 0) {
    float t = 0.0f;
    for (int w2 = 0; w2 < 16; ++w2) t += red[w2];
    loss[0] = t * (1.0f/4096.0f);
  }
}

// ---------------------------------------------------------------------------
__global__ __launch_bounds__(256) void finalize_d_kernel(
    float* __restrict__ dmat, const float* __restrict__ Minv, const float* __restrict__ diagv)
{
  const int bh = blockIdx.z;
  const int i0 = blockIdx.y*64, j0 = blockIdx.x*64;
  __shared__ float t[64][65];
  const int tx = threadIdx.x, ty = threadIdx.y;
  const size_t mbase = (size_t)bh*262144;
  for (int jj = ty; jj < 64; jj += 4)
    t[jj][tx] = Minv[mbase + (size_t)(j0+jj)*512 + i0 + tx];
  __syncthreads();
  const float dg_j = diagv[bh*512 + j0 + tx];
  for (int ii = ty; ii < 64; ii += 4) {
    const size_t idx = mbase + (size_t)(i0+ii)*512 + j0 + tx;
    dmat[idx] = dmat[idx] * (dg_j - t[tx][ii]);
  }
}

// ---------------------------------------------------------------------------
// Packed context (bh 8..95): A = masked d^T pair-packed on the fly (trunc
// hi + residual); B = pre-packed xh/xl copied straight to LDS. LDS layout
// [k2][132 words]: b128 writes (lane covers 4 consecutive words ->
// conflict-free), frag reads 2-way aliased (free). k-pair in each u32 =
// global rows (kk+2*k2, kk+2*k2+1) for BOTH operands -> slot-consistent.
__global__ __launch_bounds__(256) void context_packed_kernel(
    const float* __restrict__ dmat, const unsigned int* __restrict__ xh,
    const unsigned int* __restrict__ xl, const float* __restrict__ mv,
    float* __restrict__ ctx)
{
  const int bh = blockIdx.z + 8, b = bh / 12;   // bh 8..95
  const int q0 = blockIdx.y << 7;
  const int c0 = blockIdx.x << 7;

  __shared__ __align__(16) unsigned int AhL[16*132];
  __shared__ __align__(16) unsigned int AlL[16*132];
  __shared__ __align__(16) unsigned int BhL[16*132];
  __shared__ __align__(16) unsigned int BlL[16*132];

  const int tid = threadIdx.x;
  const int w = tid >> 6, l = tid & 63;
  const int wq = w >> 1, wc = w & 1;       // wave -> 64x64 quadrant
  const int l15 = l & 15, g = l >> 4;      // MFMA lane coords
  const int q4 = tid & 31, pp = tid >> 5;  // staging coords

  const size_t dbase = (size_t)bh*262144;
  const int xrow0 = b*256;                 // xh k2g base for this b

  float mq[4];
  {
    const float4 t4 = *(const float4*)(mv + b*512 + q0 + q4*4);
    mq[0]=t4.x; mq[1]=t4.y; mq[2]=t4.z; mq[3]=t4.w;
  }

  f32x4 acc[4][4] = {};

  for (int kk = 0; kk < 512; kk += 32) {
    __syncthreads();                       // previous iter's frag reads done
#pragma unroll
    for (int s = 0; s < 2; ++s) {
      const int k2 = pp + 8*s;             // 0..15
      const int krow = kk + 2*k2;
      // ---- A: 2 rows x 4 q, mask, trunc pair-pack ----
      const float mk0 = mv[b*512 + krow];
      const float mk1 = mv[b*512 + krow + 1];
      const uint4 r0 = *(const uint4*)(dmat + dbase + (size_t)krow*512 + q0 + q4*4);
      const uint4 r1 = *(const uint4*)(dmat + dbase + (size_t)(krow+1)*512 + q0 + q4*4);
      unsigned int hw[4], lw[4];
#pragma unroll
      for (int i = 0; i < 4; ++i) {
        unsigned int v0 = ((const unsigned int*)&r0)[i];
        unsigned int v1 = ((const unsigned int*)&r1)[i];
        v0 = ((mk0 + mq[i]) != 0.0f) ? 0u : v0;
        v1 = ((mk1 + mq[i]) != 0.0f) ? 0u : v1;
        hw[i] = __builtin_amdgcn_perm(v1, v0, 0x07060302u);
        const float f0 = __uint_as_float(v0) - __uint_as_float(v0 & 0xffff0000u);
        const float f1 = __uint_as_float(v1) - __uint_as_float(v1 & 0xffff0000u);
        lw[i] = __builtin_amdgcn_perm(__float_as_uint(f1), __float_as_uint(f0),
                                      0x07060302u);
      }
      *(uint4*)(AhL + k2*132 + q4*4) = make_uint4(hw[0], hw[1], hw[2], hw[3]);
      *(uint4*)(AlL + k2*132 + q4*4) = make_uint4(lw[0], lw[1], lw[2], lw[3]);
      // ---- B: straight copy from pre-packed xh/xl ----
      const size_t xi = (size_t)(xrow0 + (kk >> 1) + k2)*768 + c0 + q4*4;
      *(uint4*)(BhL + k2*132 + q4*4) = *(const uint4*)(xh + xi);
      *(uint4*)(BlL + k2*132 + q4*4) = *(const uint4*)(xl + xi);
    }
    __syncthreads();

    u32x4 ah[4], al[4], bhv[4], blv[4];
#pragma unroll
    for (int mi = 0; mi < 4; ++mi) {
      const int col = wq*64 + mi*16 + l15;
#pragma unroll
      for (int d2 = 0; d2 < 4; ++d2) {
        ah[mi][d2] = AhL[(4*g + d2)*132 + col];
        al[mi][d2] = AlL[(4*g + d2)*132 + col];
      }
    }
#pragma unroll
    for (int ni = 0; ni < 4; ++ni) {
      const int col = wc*64 + ni*16 + l15;
#pragma unroll
      for (int d2 = 0; d2 < 4; ++d2) {
        bhv[ni][d2] = BhL[(4*g + d2)*132 + col];
        blv[ni][d2] = BlL[(4*g + d2)*132 + col];
      }
    }

#pragma unroll
    for (int mi = 0; mi < 4; ++mi) {
      const bf16x8 Ah = __builtin_bit_cast(bf16x8, ah[mi]);
      const bf16x8 Al = __builtin_bit_cast(bf16x8, al[mi]);
#pragma unroll
      for (int ni = 0; ni < 4; ++ni) {
        const bf16x8 Bh = __builtin_bit_cast(bf16x8, bhv[ni]);
        const bf16x8 Bl = __builtin_bit_cast(bf16x8, blv[ni]);
        acc[mi][ni] = __builtin_amdgcn_mfma_f32_16x16x32_bf16(Ah, Bh, acc[mi][ni], 0, 0, 0);
        acc[mi][ni] = __builtin_amdgcn_mfma_f32_16x16x32_bf16(Ah, Bl, acc[mi][ni], 0, 0, 0);
        acc[mi][ni] = __builtin_amdgcn_mfma_f32_16x16x32_bf16(Al, Bh, acc[mi][ni], 0, 0, 0);
      }
    }
  }

#pragma unroll
  for (int mi = 0; mi < 4; ++mi) {
    const int row = q0 + wq*64 + mi*16 + g*4;
#pragma unroll
    for (int ni = 0; ni < 4; ++ni) {
      const int col = c0 + wc*64 + ni*16 + l15;
#pragma unroll
      for (int r = 0; r < 4; ++r)
        ctx[((size_t)bh*512 + row + r)*768 + col] = acc[mi][ni][r];
    }
  }
}

// ---------------------------------------------------------------------------
// Fallback context (bh 0..7): R1's in-kernel-pack MFMA version, unchanged.
__device__ __forceinline__ unsigned int pack_bf16x2(float v)
{
  const unsigned int u = __float_as_uint(v);
  const unsigned int hi = (u + 0x7FFFu + ((u >> 16) & 1u)) >> 16;  // RNE bf16(v)
  const float hf = __uint_as_float(hi << 16);
  const unsigned int lo = __float_as_uint(v - hf) >> 16;           // trunc bf16(residual)
  return hi | (lo << 16);
}

__global__ __launch_bounds__(256) void context_mfma_kernel(
    const float* __restrict__ dmat, const float* __restrict__ x,
    const float* __restrict__ mv, float* __restrict__ ctx)
{
  const int bh = blockIdx.z, b = bh / 12;
  const int q0 = blockIdx.y << 7;
  const int c0 = blockIdx.x << 7;

  __shared__ unsigned int As[32*133];
  __shared__ unsigned int Bs[32*133];

  const int tid = threadIdx.x;
  const int w = tid >> 6, l = tid & 63;
  const int wq = w >> 1, wc = w & 1;
  const int l15 = l & 15, g = l >> 4;
  const int q4 = tid & 31, kr0 = tid >> 5;

  const size_t dbase = (size_t)bh*262144;
  const size_t xbase = (size_t)b*393216;

  float mq[4];
  {
    const float4 t4 = *(const float4*)(mv + b*512 + q0 + q4*4);
    mq[0]=t4.x; mq[1]=t4.y; mq[2]=t4.z; mq[3]=t4.w;
  }

  f32x4 acc[4][4] = {};

  for (int kk = 0; kk < 512; kk += 32) {
    __syncthreads();
#pragma unroll
    for (int p = 0; p < 4; ++p) {
      const int kr = kr0 + 8*p;
      const int krow = kk + kr;
      const float mk = mv[b*512 + krow];
      const float4 av = *(const float4*)(dmat + dbase + (size_t)krow*512 + q0 + q4*4);
      const float4 bv = *(const float4*)(x + xbase + (size_t)krow*768 + c0 + q4*4);
      unsigned int* aw = As + kr*133 + q4*4;
      unsigned int* bw = Bs + kr*133 + q4*4;
      aw[0] = pack_bf16x2(((mk + mq[0]) != 0.0f) ? 0.0f : av.x);
      aw[1] = pack_bf16x2(((mk + mq[1]) != 0.0f) ? 0.0f : av.y);
      aw[2] = pack_bf16x2(((mk + mq[2]) != 0.0f) ? 0.0f : av.z);
      aw[3] = pack_bf16x2(((mk + mq[3]) != 0.0f) ? 0.0f : av.w);
      bw[0] = pack_bf16x2(bv.x);
      bw[1] = pack_bf16x2(bv.y);
      bw[2] = pack_bf16x2(bv.z);
      bw[3] = pack_bf16x2(bv.w);
    }
    __syncthreads();

    u32x4 ah[4], al[4], bhv[4], blv[4];
#pragma unroll
    for (int mi = 0; mi < 4; ++mi) {
      const unsigned int* base = As + g*8*133 + (wq*64 + mi*16 + l15);
      unsigned int u[8];
#pragma unroll
      for (int e = 0; e < 8; ++e) u[e] = base[e*133];
#pragma unroll
      for (int d2 = 0; d2 < 4; ++d2) {
        ah[mi][d2] = __builtin_amdgcn_perm(u[2*d2+1], u[2*d2], 0x05040100u);
        al[mi][d2] = __builtin_amdgcn_perm(u[2*d2+1], u[2*d2], 0x07060302u);
      }
    }
#pragma unroll
    for (int ni = 0; ni < 4; ++ni) {
      const unsigned int* base = Bs + g*8*133 + (wc*64 + ni*16 + l15);
      unsigned int u[8];
#pragma unroll
      for (int e = 0; e < 8; ++e) u[e] = base[e*133];
#pragma unroll
      for (int d2 = 0; d2 < 4; ++d2) {
        bhv[ni][d2] = __builtin_amdgcn_perm(u[2*d2+1], u[2*d2], 0x05040100u);
        blv[ni][d2] = __builtin_amdgcn_perm(u[2*d2+1], u[2*d2], 0x07060302u);
      }
    }

#pragma unroll
    for (int mi = 0; mi < 4; ++mi) {
      const bf16x8 Ah = __builtin_bit_cast(bf16x8, ah[mi]);
      const bf16x8 Al = __builtin_bit_cast(bf16x8, al[mi]);
#pragma unroll
      for (int ni = 0; ni < 4; ++ni) {
        const bf16x8 Bh = __builtin_bit_cast(bf16x8, bhv[ni]);
        const bf16x8 Bl = __builtin_bit_cast(bf16x8, blv[ni]);
        acc[mi][ni] = __builtin_amdgcn_mfma_f32_16x16x32_bf16(Ah, Bh, acc[mi][ni], 0, 0, 0);
        acc[mi][ni] = __builtin_amdgcn_mfma_f32_16x16x32_bf16(Ah, Bl, acc[mi][ni], 0, 0, 0);
        acc[mi][ni] = __builtin_amdgcn_mfma_f32_16x16x32_bf16(Al, Bh, acc[mi][ni], 0, 0, 0);
      }
    }
  }

#pragma unroll
  for (int mi = 0; mi < 4; ++mi) {
    const int row = q0 + wq*64 + mi*16 + g*4;
#pragma unroll
    for (int ni = 0; ni < 4; ++ni) {
      const int col = c0 + wc*64 + ni*16 + l15;
#pragma unroll
      for (int r = 0; r < 4; ++r)
        ctx[((size_t)bh*512 + row + r)*768 + col] = acc[mi][ni][r];
    }
  }
}

// ---------------------------------------------------------------------------
extern "C" void kernel_launch(void* const* d_in, const int* in_sizes, int n_in,
                              void* d_out, int out_size, void* d_ws, size_t ws_size,
                              hipStream_t stream)
{
  (void)in_sizes; (void)n_in; (void)out_size; (void)ws_size;

  const float* x    = (const float*)d_in[0];
  const float* mask = (const float*)d_in[1];
  const int*   roots= (const int*)d_in[2];
  const float* Wq   = (const float*)d_in[4];
  const float* bq   = (const float*)d_in[5];
  const float* Wk   = (const float*)d_in[6];
  const float* bk   = (const float*)d_in[7];
  const float* Wr   = (const float*)d_in[8];
  const float* br   = (const float*)d_in[9];

  float* out        = (float*)d_out;
  float* ctx_region = out;                 // 37748736 floats
  float* d_region   = out + 37748736;      // 25165824 floats (A -> d in place)
  float* d0_region  = out + 62914560;      // 49152 floats
  float* loss_ptr   = out + 62963712;      // 1 float

  // scratch inside the context region
  float* Qs = ctx_region;                  // 3145728 (later: xh|xl packed x)
  float* Ks = ctx_region + 3145728;        // 3145728
  float* Mv = ctx_region + 6291456;        // 25165824 (ends at 31457280)
  float* Mp = ctx_region + 31457280;       // 3145728  (ends at 34603008)
  float* Invs = ctx_region + 34603008;     // 393216   (ends at 34996224)

  unsigned int* xh = (unsigned int*)ctx_region;            // 1572864 u32
  unsigned int* xl = (unsigned int*)ctx_region + 1572864;  // 1572864 u32 (ends 3145728)

  float* ws     = (float*)d_ws;
  float* Rv     = ws;                      // 4096
  float* mv     = ws + 4096;               // 4096
  float* colsum = ws + 8192;               // 49152
  float* diagv  = ws + 57344;              // 49152

  proj_kernel   <<<dim3(6,32,2),  dim3(16,16), 0, stream>>>(x, Wq, bq, Wk, bk, Qs, Ks);
  root_kernel   <<<dim3(1024),    dim3(256),   0, stream>>>(x, Wr, br, mask, Rv, mv);
  scores_kernel <<<dim3(4,4,96),  dim3(16,16), 0, stream>>>(Qs, Ks, mv, d_region);
  pack_x_kernel <<<dim3(1536),    dim3(256),   0, stream>>>(x, xh, xl);
  colsum_kernel <<<dim3(2,96),    dim3(256),   0, stream>>>(d_region, colsum);
  buildM_kernel <<<dim3(24576),   dim3(256),   0, stream>>>(d_region, colsum, Rv, Mv);

  for (int step = 0; step < 8; ++step) {
    const int k0 = step * 64;
    gj_inv_kernel   <<<dim3(96),     dim3(256),   0, stream>>>(Mv, Mp, Invs, k0);
    gj_w_kernel     <<<dim3(4,96),   dim3(16,16), 0, stream>>>(Mv, Invs, k0);
    gj_update_kernel<<<dim3(4,4,96), dim3(16,16), 0, stream>>>(Mv, Mp, k0);
  }

  diag_d0_kernel<<<dim3(96),      dim3(512),   0, stream>>>(Mv, Rv, diagv, d0_region);
  loss_kernel   <<<dim3(1),       dim3(1024),  0, stream>>>(d0_region, roots, loss_ptr);
  finalize_d_kernel<<<dim3(8,8,96), dim3(64,4), 0, stream>>>(d_region, Mv, diagv);
  // packed context first (reads xh/xl in ctx rows of bh 0..7), then fallback
  // for bh 0..7 (overwrites xh/xl region; safe by stream order).
  context_packed_kernel<<<dim3(6,4,88), dim3(256), 0, stream>>>(d_region, xh, xl, mv, ctx_region);
  context_mfma_kernel  <<<dim3(6,4,8),  dim3(256), 0, stream>>>(d_region, x, mv, ctx_region);
}

// Round 4
// 1862.749 us; speedup vs baseline: 1.0247x; 1.0247x over previous
//
#include <hip/hip_runtime.h>
#include <hip/hip_bf16.h>
#include <math.h>

// Shapes (fixed): B=8, L=512, D=768, H=12, DK=64, N=B*L=4096, BH=96
// Output layout (floats): context[37748736] | d[25165824] | d0[49152] | loss[1]
// Scratch inside ctx region: Qs|Ks (later xh|xl), Mv, Mp, Inv, Wpack.
//
// R3 changes:
//  (1) proj -> MFMA split-precision (pack_w pre-packs Wq/Wk hi/lo pairs;
//      x trunc-packed on the fly). Same template as context_packed.
//  (2) Mp panel-row copy moved from gj_inv into gj_w (Mp panel-col values
//      are never consumed by gj_update's stored outputs). gj_inv is now a
//      pure 64-thread register inversion -> isolates its true cost.

#define INV_SQRT_D 0.03608439182435161f  // 1/sqrt(768)

typedef short bf16x8 __attribute__((ext_vector_type(8)));
typedef float f32x4 __attribute__((ext_vector_type(4)));
typedef unsigned int u32x4 __attribute__((ext_vector_type(4)));

// ---------------------------------------------------------------------------
// 8x8-per-thread fp32 GEMM micro kernel over a K-chunk of 16.
__device__ __forceinline__ void mm_micro(const float* At, const float* Bt,
                                         float acc[8][8], int tx, int ty)
{
#pragma unroll
  for (int t = 0; t < 16; ++t) {
    const float4 a0 = *(const float4*)(At + t*132 + ty*8);
    const float4 a1 = *(const float4*)(At + t*132 + ty*8 + 4);
    const float4 b0 = *(const float4*)(Bt + t*132 + tx*8);
    const float4 b1 = *(const float4*)(Bt + t*132 + tx*8 + 4);
    const float a[8] = {a0.x,a0.y,a0.z,a0.w,a1.x,a1.y,a1.z,a1.w};
    const float b[8] = {b0.x,b0.y,b0.z,b0.w,b1.x,b1.y,b1.z,b1.w};
#pragma unroll
    for (int i = 0; i < 8; ++i)
#pragma unroll
      for (int j = 0; j < 8; ++j)
        acc[i][j] = fmaf(a[i], b[j], acc[i][j]);
  }
}

// ---------------------------------------------------------------------------
// pack_w: Wq,Wk [768][768] fp32 -> hi/lo u32 pair planes [384][768].
// Pair word = (RNE-bf16 of row 2k2) | (RNE-bf16 of row 2k2+1)<<16; lo = trunc
// residual pair.
__global__ __launch_bounds__(256) void pack_w_kernel(
    const float* __restrict__ Wq, const float* __restrict__ Wk,
    unsigned int* __restrict__ Wqh, unsigned int* __restrict__ Wql,
    unsigned int* __restrict__ Wkh, unsigned int* __restrict__ Wkl)
{
  const int gid = blockIdx.x*256 + threadIdx.x;   // 0..147455
  const int m = gid >= 73728;
  const int id = m ? gid - 73728 : gid;
  const int k2 = id / 192;                        // 0..383
  const int cc = (id - k2*192) * 4;
  const float* W = m ? Wk : Wq;
  unsigned int* Oh = m ? Wkh : Wqh;
  unsigned int* Ol = m ? Wkl : Wql;
  const unsigned int* wb = (const unsigned int*)W;
  const size_t s0 = (size_t)(2*k2)*768 + cc;
  const uint4 r0 = *(const uint4*)(wb + s0);
  const uint4 r1 = *(const uint4*)(wb + s0 + 768);
  unsigned int hw[4], lw[4];
#pragma unroll
  for (int i = 0; i < 4; ++i) {
    const unsigned int u0 = ((const unsigned int*)&r0)[i];
    const unsigned int u1 = ((const unsigned int*)&r1)[i];
    const unsigned int h0 = (u0 + 0x7FFFu + ((u0 >> 16) & 1u)) >> 16;
    const unsigned int h1 = (u1 + 0x7FFFu + ((u1 >> 16) & 1u)) >> 16;
    hw[i] = h0 | (h1 << 16);
    const float rs0 = __uint_as_float(u0) - __uint_as_float(h0 << 16);
    const float rs1 = __uint_as_float(u1) - __uint_as_float(h1 << 16);
    lw[i] = __builtin_amdgcn_perm(__float_as_uint(rs1), __float_as_uint(rs0),
                                  0x07060302u);
  }
  const size_t o = (size_t)k2*768 + cc;
  *(uint4*)(Oh + o) = make_uint4(hw[0], hw[1], hw[2], hw[3]);
  *(uint4*)(Ol + o) = make_uint4(lw[0], lw[1], lw[2], lw[3]);
}

// ---------------------------------------------------------------------------
// proj via MFMA split: Q = (x@Wq+bq)/sqrt(D), K = x@Wk+bk.
// A = x (trunc pair-packed on the fly), B = pre-packed W planes (pure copy).
// Tiles 128x128, K=768 in chunks of 32 (16 pairs).
__global__ __launch_bounds__(256) void proj_mfma_kernel(
    const float* __restrict__ x,
    const unsigned int* __restrict__ Wqh, const unsigned int* __restrict__ Wql,
    const unsigned int* __restrict__ Wkh, const unsigned int* __restrict__ Wkl,
    const float* __restrict__ bq, const float* __restrict__ bk,
    float* __restrict__ Q, float* __restrict__ Kc)
{
  const unsigned int* Wh; const unsigned int* Wl;
  const float* bias; float* out; float scale;
  if (blockIdx.z == 0) { Wh = Wqh; Wl = Wql; bias = bq; out = Q;  scale = INV_SQRT_D; }
  else                 { Wh = Wkh; Wl = Wkl; bias = bk; out = Kc; scale = 1.0f; }

  const int row0 = blockIdx.y << 7;        // n
  const int col0 = blockIdx.x << 7;        // out dim

  __shared__ __align__(16) unsigned int AhL[16*132];
  __shared__ __align__(16) unsigned int AlL[16*132];
  __shared__ __align__(16) unsigned int BhL[16*132];
  __shared__ __align__(16) unsigned int BlL[16*132];

  const int tid = threadIdx.x;
  const int w = tid >> 6, l = tid & 63;
  const int wq = w >> 1, wc = w & 1;
  const int l15 = l & 15, g = l >> 4;
  const int q4 = tid & 31, pp = tid >> 5;
  const int an = tid & 127, ahh = tid >> 7;  // A-staging: row, k-half

  f32x4 acc[4][4] = {};

  for (int kk = 0; kk < 768; kk += 32) {
    __syncthreads();
    // ---- B: straight copy of packed W planes ----
#pragma unroll
    for (int s = 0; s < 2; ++s) {
      const int k2 = pp + 8*s;
      const size_t wi = (size_t)((kk >> 1) + k2)*768 + col0 + q4*4;
      *(uint4*)(BhL + k2*132 + q4*4) = *(const uint4*)(Wh + wi);
      *(uint4*)(BlL + k2*132 + q4*4) = *(const uint4*)(Wl + wi);
    }
    // ---- A: x row, 16 features, trunc pair-pack ----
    {
      const float* xr = x + (size_t)(row0 + an)*768 + kk + ahh*16;
      const uint4 v0 = *(const uint4*)(xr + 0);
      const uint4 v1 = *(const uint4*)(xr + 4);
      const uint4 v2 = *(const uint4*)(xr + 8);
      const uint4 v3 = *(const uint4*)(xr + 12);
      const unsigned int uu[16] = {v0.x,v0.y,v0.z,v0.w, v1.x,v1.y,v1.z,v1.w,
                                   v2.x,v2.y,v2.z,v2.w, v3.x,v3.y,v3.z,v3.w};
#pragma unroll
      for (int pr = 0; pr < 8; ++pr) {
        const unsigned int a0 = uu[2*pr], a1 = uu[2*pr+1];
        const unsigned int hw = __builtin_amdgcn_perm(a1, a0, 0x07060302u);
        const float f0 = __uint_as_float(a0) - __uint_as_float(a0 & 0xffff0000u);
        const float f1 = __uint_as_float(a1) - __uint_as_float(a1 & 0xffff0000u);
        const unsigned int lw = __builtin_amdgcn_perm(__float_as_uint(f1),
                                                      __float_as_uint(f0),
                                                      0x07060302u);
        const int k2 = ahh*8 + pr;
        AhL[k2*132 + an] = hw;
        AlL[k2*132 + an] = lw;
      }
    }
    __syncthreads();

    u32x4 ah[4], al[4], bhv[4], blv[4];
#pragma unroll
    for (int mi = 0; mi < 4; ++mi) {
      const int col = wq*64 + mi*16 + l15;
#pragma unroll
      for (int d2 = 0; d2 < 4; ++d2) {
        ah[mi][d2] = AhL[(4*g + d2)*132 + col];
        al[mi][d2] = AlL[(4*g + d2)*132 + col];
      }
    }
#pragma unroll
    for (int ni = 0; ni < 4; ++ni) {
      const int col = wc*64 + ni*16 + l15;
#pragma unroll
      for (int d2 = 0; d2 < 4; ++d2) {
        bhv[ni][d2] = BhL[(4*g + d2)*132 + col];
        blv[ni][d2] = BlL[(4*g + d2)*132 + col];
      }
    }

#pragma unroll
    for (int mi = 0; mi < 4; ++mi) {
      const bf16x8 Ah = __builtin_bit_cast(bf16x8, ah[mi]);
      const bf16x8 Al = __builtin_bit_cast(bf16x8, al[mi]);
#pragma unroll
      for (int ni = 0; ni < 4; ++ni) {
        const bf16x8 Bh = __builtin_bit_cast(bf16x8, bhv[ni]);
        const bf16x8 Bl = __builtin_bit_cast(bf16x8, blv[ni]);
        acc[mi][ni] = __builtin_amdgcn_mfma_f32_16x16x32_bf16(Ah, Bh, acc[mi][ni], 0, 0, 0);
        acc[mi][ni] = __builtin_amdgcn_mfma_f32_16x16x32_bf16(Ah, Bl, acc[mi][ni], 0, 0, 0);
        acc[mi][ni] = __builtin_amdgcn_mfma_f32_16x16x32_bf16(Al, Bh, acc[mi][ni], 0, 0, 0);
      }
    }
  }

#pragma unroll
  for (int mi = 0; mi < 4; ++mi) {
    const int row = row0 + wq*64 + mi*16 + g*4;
#pragma unroll
    for (int ni = 0; ni < 4; ++ni) {
      const int col = col0 + wc*64 + ni*16 + l15;
      const float bs = bias[col];
#pragma unroll
      for (int r = 0; r < 4; ++r)
        out[(size_t)(row + r)*768 + col] = (acc[mi][ni][r] + bs) * scale;
    }
  }
}

// ---------------------------------------------------------------------------
__global__ __launch_bounds__(256) void root_kernel(
    const float* __restrict__ x, const float* __restrict__ Wr,
    const float* __restrict__ br, const float* __restrict__ mask,
    float* __restrict__ Rv, float* __restrict__ mv)
{
  const int n = blockIdx.x*4 + (threadIdx.x >> 6);
  const int lane = threadIdx.x & 63;
  float s = 0.0f;
  for (int c = lane; c < 768; c += 64) s += x[(size_t)n*768 + c] * Wr[c];
#pragma unroll
  for (int off = 32; off > 0; off >>= 1) s += __shfl_down(s, off, 64);
  if (lane == 0) {
    const float root = s + br[0];
    const float m = mask[n] * (-1e-4f);
    Rv[n] = expf(fmaxf(root - m*50.0f, -40.0f));
    mv[n] = m;
  }
}

// ---------------------------------------------------------------------------
__global__ __launch_bounds__(256) void scores_kernel(
    const float* __restrict__ Qs, const float* __restrict__ Ks,
    const float* __restrict__ mv, float* __restrict__ A)
{
  const int bh = blockIdx.z, b = bh / 12, h = bh % 12;
  const int i0 = blockIdx.y * 128, j0 = blockIdx.x * 128;
  __shared__ __align__(16) float At[16*132];
  __shared__ __align__(16) float Bt[16*132];
  const int tx = threadIdx.x, ty = threadIdx.y;
  const int tid = ty*16 + tx;
  const int lt = tid & 15, lr = tid >> 4;
  const size_t qbase = (size_t)(b*512 + i0)*768 + h*64;
  const size_t kbase = (size_t)(b*512 + j0)*768 + h*64;

  float acc[8][8] = {};

  for (int kk = 0; kk < 64; kk += 16) {
#pragma unroll
    for (int u = 0; u < 8; ++u) {
      const int r = lr + 16*u;
      At[lt*132 + r] = Qs[qbase + (size_t)r*768 + kk + lt];
      Bt[lt*132 + r] = Ks[kbase + (size_t)r*768 + kk + lt];
    }
    __syncthreads();
    mm_micro(At, Bt, acc, tx, ty);
    __syncthreads();
  }

  float mi[8], mj[8];
#pragma unroll
  for (int i = 0; i < 8; ++i) mi[i] = mv[b*512 + i0 + ty*8 + i];
#pragma unroll
  for (int j = 0; j < 8; ++j) mj[j] = mv[b*512 + j0 + tx*8 + j];

#pragma unroll
  for (int i = 0; i < 8; ++i) {
    const size_t rowb = (size_t)(bh*512 + i0 + ty*8 + i)*512;
#pragma unroll
    for (int j = 0; j < 8; j += 4) {
      float4 v;
      v.x = expf(fmaxf(acc[i][j+0] - (mi[i]+mj[j+0])*50.0f, -40.0f));
      v.y = expf(fmaxf(acc[i][j+1] - (mi[i]+mj[j+1])*50.0f, -40.0f));
      v.z = expf(fmaxf(acc[i][j+2] - (mi[i]+mj[j+2])*50.0f, -40.0f));
      v.w = expf(fmaxf(acc[i][j+3] - (mi[i]+mj[j+3])*50.0f, -40.0f));
      *(float4*)(A + rowb + j0 + tx*8 + j) = v;
    }
  }
}

// ---------------------------------------------------------------------------
// pack_x: x -> xh/xl pair planes [k2g][768] (k2g = b*256 + k2).
__global__ __launch_bounds__(256) void pack_x_kernel(
    const float* __restrict__ x, unsigned int* __restrict__ xh,
    unsigned int* __restrict__ xl)
{
  const int gid = blockIdx.x*256 + threadIdx.x;   // 0..393215
  const int k2g = gid / 192;                      // 0..2047
  const int cc  = (gid - k2g*192) * 4;
  const unsigned int* xb = (const unsigned int*)x;
  const size_t s0 = (size_t)(2*k2g)*768 + cc;
  const uint4 r0 = *(const uint4*)(xb + s0);
  const uint4 r1 = *(const uint4*)(xb + s0 + 768);
  unsigned int hw[4], lw[4];
#pragma unroll
  for (int i = 0; i < 4; ++i) {
    const unsigned int u0 = ((const unsigned int*)&r0)[i];
    const unsigned int u1 = ((const unsigned int*)&r1)[i];
    const unsigned int h0 = (u0 + 0x7FFFu + ((u0 >> 16) & 1u)) >> 16;
    const unsigned int h1 = (u1 + 0x7FFFu + ((u1 >> 16) & 1u)) >> 16;
    hw[i] = h0 | (h1 << 16);
    const float rs0 = __uint_as_float(u0) - __uint_as_float(h0 << 16);
    const float rs1 = __uint_as_float(u1) - __uint_as_float(h1 << 16);
    lw[i] = __builtin_amdgcn_perm(__float_as_uint(rs1), __float_as_uint(rs0),
                                  0x07060302u);
  }
  const size_t o = (size_t)k2g*768 + cc;
  *(uint4*)(xh + o) = make_uint4(hw[0], hw[1], hw[2], hw[3]);
  *(uint4*)(xl + o) = make_uint4(lw[0], lw[1], lw[2], lw[3]);
}

// ---------------------------------------------------------------------------
__global__ void colsum_kernel(const float* __restrict__ A, float* __restrict__ colsum)
{
  const int bh = blockIdx.y;
  const int j = blockIdx.x*256 + threadIdx.x;
  const float* Ab = A + (size_t)bh*262144;
  float s = 0.0f;
  for (int i = 0; i < 512; ++i) s += Ab[(size_t)i*512 + j];
  colsum[bh*512 + j] = s;
}

// ---------------------------------------------------------------------------
__global__ void buildM_kernel(const float* __restrict__ A, const float* __restrict__ colsum,
                              const float* __restrict__ Rv, float* __restrict__ M)
{
  const size_t g = ((size_t)blockIdx.x*256 + threadIdx.x)*4;
  const int bh = (int)(g >> 18);
  const int i = (int)((g >> 9) & 511);
  const int j = (int)(g & 511);
  const float4 a = *(const float4*)(A + g);
  float4 v; v.x = -a.x; v.y = -a.y; v.z = -a.z; v.w = -a.w;
  if (i >= j && i < j+4) {
    const float dadd = colsum[bh*512 + i] + Rv[(bh/12)*512 + i];
    ((float*)&v)[i - j] += dadd;
  }
  *(float4*)(M + g) = v;
}

// ---------------------------------------------------------------------------
// gj_inv: pure 64x64 register inversion, one wave per matrix. (Mp copy moved
// to gj_w.) Batched pivot-row gather for ILP; math identical to R1/R2.
__global__ __launch_bounds__(64) void gj_inv_kernel(
    const float* __restrict__ M, float* __restrict__ Inv, int k0)
{
  const float* const Mg = M + (size_t)blockIdx.x * 262144;
  float* const Ig = Inv + (size_t)blockIdx.x * 4096;
  const int lane = threadIdx.x;

  float w[64];
  {
    const float* src = Mg + (size_t)(k0 + lane)*512 + k0;
#pragma unroll
    for (int q = 0; q < 16; ++q) {
      const float4 t4 = *(const float4*)(src + q*4);
      w[q*4+0]=t4.x; w[q*4+1]=t4.y; w[q*4+2]=t4.z; w[q*4+3]=t4.w;
    }
  }

  float fcur = w[0];                      // = w[kk] at loop top
#pragma unroll 1
  for (int kk = 0; kk < 64; ++kk) {
    float rj[64];
#pragma unroll
    for (int j = 0; j < 64; ++j) rj[j] = __shfl(w[j], kk);
    const float pv = __shfl(fcur, kk);    // old M[kk][kk]
    const float p  = 1.0f / pv;
    const bool isp = (lane == kk);
    const float alpha = isp ? p : -fcur * p;
    float fnext = fcur;
#pragma unroll
    for (int j = 0; j < 64; ++j) {
      const float base = isp ? 0.0f : w[j];
      float val = fmaf(alpha, rj[j], base);
      if (j == kk) val = alpha;           // uniform cond -> select
      w[j] = val;
      if (j == kk + 1) fnext = val;       // uniform cond -> select
    }
    fcur = fnext;
  }

  {
    float* dst = Ig + lane*64;
#pragma unroll
    for (int q = 0; q < 16; ++q)
      *(float4*)(dst + q*4) = make_float4(w[q*4+0], w[q*4+1], w[q*4+2], w[q*4+3]);
  }
}

// ---------------------------------------------------------------------------
// gj_w: W into panel cols + Mp panel-row copy (16 rows per block).
__global__ __launch_bounds__(256) void gj_w_kernel(
    float* __restrict__ M, float* __restrict__ Mp,
    const float* __restrict__ Inv, int k0)
{
  const int bh = blockIdx.y;
  const int row0 = blockIdx.x * 128;
  float* const Mg = M + (size_t)bh*262144;
  float* const Mpg = Mp + (size_t)bh*32768;
  const float* const Ig = Inv + (size_t)bh*4096;

  __shared__ __align__(16) float Ct[16*132];
  __shared__ __align__(16) float It[16*68];

  const int tx = threadIdx.x, ty = threadIdx.y;   // (16,16)
  const int tid = ty*16 + tx;
  const int lt = tid & 15, lr = tid >> 4;

  // ---- Mp copy: this block copies panel rows rq*16 .. rq*16+15 ----
  {
    const int rq = blockIdx.x;            // 0..3
    const int c4 = (tid & 127) * 4;
    const int rr = tid >> 7;              // 0..1
#pragma unroll
    for (int u = 0; u < 8; ++u) {
      const int r = rq*16 + u*2 + rr;
      *(float4*)(Mpg + (size_t)r*512 + c4) =
          *(const float4*)(Mg + (size_t)(k0 + r)*512 + c4);
    }
  }

  float acc[8][4] = {};

  for (int kc = 0; kc < 64; kc += 16) {
#pragma unroll
    for (int u = 0; u < 8; ++u) {
      const int r = lr + 16*u;
      Ct[lt*132 + r] = Mg[(size_t)(row0 + r)*512 + k0 + kc + lt];   // C slice
    }
    {
      const int j = tid & 63, t0 = tid >> 6;      // t0 = 0..3
#pragma unroll
      for (int u = 0; u < 4; ++u) {
        const int t = t0*4 + u;
        It[t*68 + j] = Ig[(kc + t)*64 + j];
      }
    }
    __syncthreads();
#pragma unroll
    for (int t = 0; t < 16; ++t) {
      const float4 a0 = *(const float4*)(Ct + t*132 + ty*8);
      const float4 a1 = *(const float4*)(Ct + t*132 + ty*8 + 4);
      const float4 b  = *(const float4*)(It + t*68 + tx*4);
      const float a[8] = {a0.x,a0.y,a0.z,a0.w,a1.x,a1.y,a1.z,a1.w};
      const float bb[4] = {b.x,b.y,b.z,b.w};
#pragma unroll
      for (int i = 0; i < 8; ++i)
#pragma unroll
        for (int j = 0; j < 4; ++j)
          acc[i][j] = fmaf(a[i], bb[j], acc[i][j]);
    }
    __syncthreads();
  }

#pragma unroll
  for (int i = 0; i < 8; ++i) {
    const int irow = row0 + ty*8 + i;
    float4 v;
    if (irow >= k0 && irow < k0 + 64) {
      v = *(const float4*)(Ig + (irow - k0)*64 + tx*4);   // A11inv rows
    } else {
      v = make_float4(-acc[i][0], -acc[i][1], -acc[i][2], -acc[i][3]);
    }
    *(float4*)(Mg + (size_t)irow*512 + k0 + tx*4) = v;
  }
}

// ---------------------------------------------------------------------------
__global__ __launch_bounds__(256) void gj_update_kernel(
    float* __restrict__ M, const float* __restrict__ Mp, int k0)
{
  const int bh = blockIdx.z;
  const int row0 = blockIdx.y * 128, col0 = blockIdx.x * 128;
  float* const Mg = M + (size_t)bh*262144;
  const float* const Mpg = Mp + (size_t)bh*32768;

  __shared__ __align__(16) float At[16*132];
  __shared__ __align__(16) float Bt[16*132];
  const int tx = threadIdx.x, ty = threadIdx.y;
  const int tid = ty*16 + tx;
  const int lt = tid & 15, lr = tid >> 4;
  const int bc = tid & 127, btr = tid >> 7;

  float acc[8][8] = {};

  for (int kc = 0; kc < 64; kc += 16) {
#pragma unroll
    for (int u = 0; u < 8; ++u) {
      const int r = lr + 16*u;
      At[lt*132 + r] = Mg[(size_t)(row0 + r)*512 + k0 + kc + lt];     // W slice
    }
#pragma unroll
    for (int u = 0; u < 8; ++u) {
      const int t = btr + 2*u;
      Bt[t*132 + bc] = Mpg[(size_t)(kc + t)*512 + col0 + bc];         // Mp_old
    }
    __syncthreads();
    mm_micro(At, Bt, acc, tx, ty);
    __syncthreads();
  }

#pragma unroll
  for (int ii = 0; ii < 8; ++ii) {
    const int irow = row0 + ty*8 + ii;
    const bool inP = (irow >= k0) && (irow < k0 + 64);
#pragma unroll
    for (int jj = 0; jj < 8; jj += 4) {
      const int jcol = col0 + tx*8 + jj;
      if (jcol >= k0 && jcol < k0 + 64) continue;   // panel cols hold W
      float* cell = Mg + (size_t)irow*512 + jcol;
      float4 v = make_float4(acc[ii][jj+0], acc[ii][jj+1], acc[ii][jj+2], acc[ii][jj+3]);
      if (!inP) {
        const float4 o = *(const float4*)cell;
        v.x += o.x; v.y += o.y; v.z += o.z; v.w += o.w;
      }
      *(float4*)cell = v;
    }
  }
}

// ---------------------------------------------------------------------------
__global__ void diag_d0_kernel(const float* __restrict__ Minv, const float* __restrict__ Rv,
                               float* __restrict__ diagv, float* __restrict__ d0)
{
  const int bh = blockIdx.x, l = threadIdx.x;
  const float dg = Minv[(size_t)bh*262144 + (size_t)l*513];
  diagv[bh*512 + l] = dg;
  d0[bh*512 + l] = Rv[(bh/12)*512 + l] * dg;
}

// ---------------------------------------------------------------------------
__global__ __launch_bounds__(1024) void loss_kernel(const float* __restrict__ d0,
                                                    const int* __restrict__ labels,
                                                    float* __restrict__ loss)
{
  float acc = 0.0f;
  for (int n = threadIdx.x; n < 4096; n += 1024) {
    if (labels[n] != 0) {
      const int b = n >> 9, l = n & 511;
      float s = 0.0f;
#pragma unroll
      for (int h = 0; h < 12; ++h) {
        float p = d0[(size_t)(b*12 + h)*512 + l];
        p = fminf(fmaxf(p, 1e-5f), 1.0f - 1e-5f);
        s -= logf(p);
      }
      acc += s;
    }
  }
  __shared__ float red[16];
#pragma unroll
  for (int off = 32; off > 0; off >>= 1) acc += __shfl_down(acc, off, 64);
  const int wv = threadIdx.x >> 6, ln = threadIdx.x & 63;
  if (ln == 0) red[wv] = acc;
  __syncthreads();
  if (threadIdx.x == 0) {
    float t = 0.0f;
    for (int w2 = 0; w2 < 16; ++w2) t += red[w2];
    loss[0] = t * (1.0f/4096.0f);
  }
}

// ---------------------------------------------------------------------------
__global__ __launch_bounds__(256) void finalize_d_kernel(
    float* __restrict__ dmat, const float* __restrict__ Minv, const float* __restrict__ diagv)
{
  const int bh = blockIdx.z;
  const int i0 = blockIdx.y*64, j0 = blockIdx.x*64;
  __shared__ float t[64][65];
  const int tx = threadIdx.x, ty = threadIdx.y;
  const size_t mbase = (size_t)bh*262144;
  for (int jj = ty; jj < 64; jj += 4)
    t[jj][tx] = Minv[mbase + (size_t)(j0+jj)*512 + i0 + tx];
  __syncthreads();
  const float dg_j = diagv[bh*512 + j0 + tx];
  for (int ii = ty; ii < 64; ii += 4) {
    const size_t idx = mbase + (size_t)(i0+ii)*512 + j0 + tx;
    dmat[idx] = dmat[idx] * (dg_j - t[tx][ii]);
  }
}

// ---------------------------------------------------------------------------
// Packed context (bh 8..95).
__global__ __launch_bounds__(256) void context_packed_kernel(
    const float* __restrict__ dmat, const unsigned int* __restrict__ xh,
    const unsigned int* __restrict__ xl, const float* __restrict__ mv,
    float* __restrict__ ctx)
{
  const int bh = blockIdx.z + 8, b = bh / 12;   // bh 8..95
  const int q0 = blockIdx.y << 7;
  const int c0 = blockIdx.x << 7;

  __shared__ __align__(16) unsigned int AhL[16*132];
  __shared__ __align__(16) unsigned int AlL[16*132];
  __shared__ __align__(16) unsigned int BhL[16*132];
  __shared__ __align__(16) unsigned int BlL[16*132];

  const int tid = threadIdx.x;
  const int w = tid >> 6, l = tid & 63;
  const int wq = w >> 1, wc = w & 1;
  const int l15 = l & 15, g = l >> 4;
  const int q4 = tid & 31, pp = tid >> 5;

  const size_t dbase = (size_t)bh*262144;
  const int xrow0 = b*256;

  float mq[4];
  {
    const float4 t4 = *(const float4*)(mv + b*512 + q0 + q4*4);
    mq[0]=t4.x; mq[1]=t4.y; mq[2]=t4.z; mq[3]=t4.w;
  }

  f32x4 acc[4][4] = {};

  for (int kk = 0; kk < 512; kk += 32) {
    __syncthreads();
#pragma unroll
    for (int s = 0; s < 2; ++s) {
      const int k2 = pp + 8*s;
      const int krow = kk + 2*k2;
      const float mk0 = mv[b*512 + krow];
      const float mk1 = mv[b*512 + krow + 1];
      const uint4 r0 = *(const uint4*)(dmat + dbase + (size_t)krow*512 + q0 + q4*4);
      const uint4 r1 = *(const uint4*)(dmat + dbase + (size_t)(krow+1)*512 + q0 + q4*4);
      unsigned int hw[4], lw[4];
#pragma unroll
      for (int i = 0; i < 4; ++i) {
        unsigned int v0 = ((const unsigned int*)&r0)[i];
        unsigned int v1 = ((const unsigned int*)&r1)[i];
        v0 = ((mk0 + mq[i]) != 0.0f) ? 0u : v0;
        v1 = ((mk1 + mq[i]) != 0.0f) ? 0u : v1;
        hw[i] = __builtin_amdgcn_perm(v1, v0, 0x07060302u);
        const float f0 = __uint_as_float(v0) - __uint_as_float(v0 & 0xffff0000u);
        const float f1 = __uint_as_float(v1) - __uint_as_float(v1 & 0xffff0000u);
        lw[i] = __builtin_amdgcn_perm(__float_as_uint(f1), __float_as_uint(f0),
                                      0x07060302u);
      }
      *(uint4*)(AhL + k2*132 + q4*4) = make_uint4(hw[0], hw[1], hw[2], hw[3]);
      *(uint4*)(AlL + k2*132 + q4*4) = make_uint4(lw[0], lw[1], lw[2], lw[3]);
      const size_t xi = (size_t)(xrow0 + (kk >> 1) + k2)*768 + c0 + q4*4;
      *(uint4*)(BhL + k2*132 + q4*4) = *(const uint4*)(xh + xi);
      *(uint4*)(BlL + k2*132 + q4*4) = *(const uint4*)(xl + xi);
    }
    __syncthreads();

    u32x4 ah[4], al[4], bhv[4], blv[4];
#pragma unroll
    for (int mi = 0; mi < 4; ++mi) {
      const int col = wq*64 + mi*16 + l15;
#pragma unroll
      for (int d2 = 0; d2 < 4; ++d2) {
        ah[mi][d2] = AhL[(4*g + d2)*132 + col];
        al[mi][d2] = AlL[(4*g + d2)*132 + col];
      }
    }
#pragma unroll
    for (int ni = 0; ni < 4; ++ni) {
      const int col = wc*64 + ni*16 + l15;
#pragma unroll
      for (int d2 = 0; d2 < 4; ++d2) {
        bhv[ni][d2] = BhL[(4*g + d2)*132 + col];
        blv[ni][d2] = BlL[(4*g + d2)*132 + col];
      }
    }

#pragma unroll
    for (int mi = 0; mi < 4; ++mi) {
      const bf16x8 Ah = __builtin_bit_cast(bf16x8, ah[mi]);
      const bf16x8 Al = __builtin_bit_cast(bf16x8, al[mi]);
#pragma unroll
      for (int ni = 0; ni < 4; ++ni) {
        const bf16x8 Bh = __builtin_bit_cast(bf16x8, bhv[ni]);
        const bf16x8 Bl = __builtin_bit_cast(bf16x8, blv[ni]);
        acc[mi][ni] = __builtin_amdgcn_mfma_f32_16x16x32_bf16(Ah, Bh, acc[mi][ni], 0, 0, 0);
        acc[mi][ni] = __builtin_amdgcn_mfma_f32_16x16x32_bf16(Ah, Bl, acc[mi][ni], 0, 0, 0);
        acc[mi][ni] = __builtin_amdgcn_mfma_f32_16x16x32_bf16(Al, Bh, acc[mi][ni], 0, 0, 0);
      }
    }
  }

#pragma unroll
  for (int mi = 0; mi < 4; ++mi) {
    const int row = q0 + wq*64 + mi*16 + g*4;
#pragma unroll
    for (int ni = 0; ni < 4; ++ni) {
      const int col = c0 + wc*64 + ni*16 + l15;
#pragma unroll
      for (int r = 0; r < 4; ++r)
        ctx[((size_t)bh*512 + row + r)*768 + col] = acc[mi][ni][r];
    }
  }
}

// ---------------------------------------------------------------------------
// Fallback context (bh 0..7): in-kernel pack.
__device__ __forceinline__ unsigned int pack_bf16x2(float v)
{
  const unsigned int u = __float_as_uint(v);
  const unsigned int hi = (u + 0x7FFFu + ((u >> 16) & 1u)) >> 16;
  const float hf = __uint_as_float(hi << 16);
  const unsigned int lo = __float_as_uint(v - hf) >> 16;
  return hi | (lo << 16);
}

__global__ __launch_bounds__(256) void context_mfma_kernel(
    const float* __restrict__ dmat, const float* __restrict__ x,
    const float* __restrict__ mv, float* __restrict__ ctx)
{
  const int bh = blockIdx.z, b = bh / 12;
  const int q0 = blockIdx.y << 7;
  const int c0 = blockIdx.x << 7;

  __shared__ unsigned int As[32*133];
  __shared__ unsigned int Bs[32*133];

  const int tid = threadIdx.x;
  const int w = tid >> 6, l = tid & 63;
  const int wq = w >> 1, wc = w & 1;
  const int l15 = l & 15, g = l >> 4;
  const int q4 = tid & 31, kr0 = tid >> 5;

  const size_t dbase = (size_t)bh*262144;
  const size_t xbase = (size_t)b*393216;

  float mq[4];
  {
    const float4 t4 = *(const float4*)(mv + b*512 + q0 + q4*4);
    mq[0]=t4.x; mq[1]=t4.y; mq[2]=t4.z; mq[3]=t4.w;
  }

  f32x4 acc[4][4] = {};

  for (int kk = 0; kk < 512; kk += 32) {
    __syncthreads();
#pragma unroll
    for (int p = 0; p < 4; ++p) {
      const int kr = kr0 + 8*p;
      const int krow = kk + kr;
      const float mk = mv[b*512 + krow];
      const float4 av = *(const float4*)(dmat + dbase + (size_t)krow*512 + q0 + q4*4);
      const float4 bv = *(const float4*)(x + xbase + (size_t)krow*768 + c0 + q4*4);
      unsigned int* aw = As + kr*133 + q4*4;
      unsigned int* bw = Bs + kr*133 + q4*4;
      aw[0] = pack_bf16x2(((mk + mq[0]) != 0.0f) ? 0.0f : av.x);
      aw[1] = pack_bf16x2(((mk + mq[1]) != 0.0f) ? 0.0f : av.y);
      aw[2] = pack_bf16x2(((mk + mq[2]) != 0.0f) ? 0.0f : av.z);
      aw[3] = pack_bf16x2(((mk + mq[3]) != 0.0f) ? 0.0f : av.w);
      bw[0] = pack_bf16x2(bv.x);
      bw[1] = pack_bf16x2(bv.y);
      bw[2] = pack_bf16x2(bv.z);
      bw[3] = pack_bf16x2(bv.w);
    }
    __syncthreads();

    u32x4 ah[4], al[4], bhv[4], blv[4];
#pragma unroll
    for (int mi = 0; mi < 4; ++mi) {
      const unsigned int* base = As + g*8*133 + (wq*64 + mi*16 + l15);
      unsigned int u[8];
#pragma unroll
      for (int e = 0; e < 8; ++e) u[e] = base[e*133];
#pragma unroll
      for (int d2 = 0; d2 < 4; ++d2) {
        ah[mi][d2] = __builtin_amdgcn_perm(u[2*d2+1], u[2*d2], 0x05040100u);
        al[mi][d2] = __builtin_amdgcn_perm(u[2*d2+1], u[2*d2], 0x07060302u);
      }
    }
#pragma unroll
    for (int ni = 0; ni < 4; ++ni) {
      const unsigned int* base = Bs + g*8*133 + (wc*64 + ni*16 + l15);
      unsigned int u[8];
#pragma unroll
      for (int e = 0; e < 8; ++e) u[e] = base[e*133];
#pragma unroll
      for (int d2 = 0; d2 < 4; ++d2) {
        bhv[ni][d2] = __builtin_amdgcn_perm(u[2*d2+1], u[2*d2], 0x05040100u);
        blv[ni][d2] = __builtin_amdgcn_perm(u[2*d2+1], u[2*d2], 0x07060302u);
      }
    }

#pragma unroll
    for (int mi = 0; mi < 4; ++mi) {
      const bf16x8 Ah = __builtin_bit_cast(bf16x8, ah[mi]);
      const bf16x8 Al = __builtin_bit_cast(bf16x8, al[mi]);
#pragma unroll
      for (int ni = 0; ni < 4; ++ni) {
        const bf16x8 Bh = __builtin_bit_cast(bf16x8, bhv[ni]);
        const bf16x8 Bl = __builtin_bit_cast(bf16x8, blv[ni]);
        acc[mi][ni] = __builtin_amdgcn_mfma_f32_16x16x32_bf16(Ah, Bh, acc[mi][ni], 0, 0, 0);
        acc[mi][ni] = __builtin_amdgcn_mfma_f32_16x16x32_bf16(Ah, Bl, acc[mi][ni], 0, 0, 0);
        acc[mi][ni] = __builtin_amdgcn_mfma_f32_16x16x32_bf16(Al, Bh, acc[mi][ni], 0, 0, 0);
      }
    }
  }

#pragma unroll
  for (int mi = 0; mi < 4; ++mi) {
    const int row = q0 + wq*64 + mi*16 + g*4;
#pragma unroll
    for (int ni = 0; ni < 4; ++ni) {
      const int col = c0 + wc*64 + ni*16 + l15;
#pragma unroll
      for (int r = 0; r < 4; ++r)
        ctx[((size_t)bh*512 + row + r)*768 + col] = acc[mi][ni][r];
    }
  }
}

// ---------------------------------------------------------------------------
extern "C" void kernel_launch(void* const* d_in, const int* in_sizes, int n_in,
                              void* d_out, int out_size, void* d_ws, size_t ws_size,
                              hipStream_t stream)
{
  (void)in_sizes; (void)n_in; (void)out_size; (void)ws_size;

  const float* x    = (const float*)d_in[0];
  const float* mask = (const float*)d_in[1];
  const int*   roots= (const int*)d_in[2];
  const float* Wq   = (const float*)d_in[4];
  const float* bq   = (const float*)d_in[5];
  const float* Wk   = (const float*)d_in[6];
  const float* bk   = (const float*)d_in[7];
  const float* Wr   = (const float*)d_in[8];
  const float* br   = (const float*)d_in[9];

  float* out        = (float*)d_out;
  float* ctx_region = out;                 // 37748736 floats
  float* d_region   = out + 37748736;      // 25165824 floats (A -> d in place)
  float* d0_region  = out + 62914560;      // 49152 floats
  float* loss_ptr   = out + 62963712;      // 1 float

  // scratch inside the context region
  float* Qs = ctx_region;                  // 3145728 (later: xh|xl packed x)
  float* Ks = ctx_region + 3145728;        // 3145728
  float* Mv = ctx_region + 6291456;        // 25165824 (ends at 31457280)
  float* Mp = ctx_region + 31457280;       // 3145728  (ends at 34603008)
  float* Invs = ctx_region + 34603008;     // 393216   (ends at 34996224)

  unsigned int* xh = (unsigned int*)ctx_region;            // 1572864 u32
  unsigned int* xl = (unsigned int*)ctx_region + 1572864;  // ends 3145728

  // packed W planes: 4 x 294912 u32 starting at 34996224 (ends 36175872)
  unsigned int* Wqh = (unsigned int*)ctx_region + 34996224;
  unsigned int* Wql = Wqh + 294912;
  unsigned int* Wkh = Wql + 294912;
  unsigned int* Wkl = Wkh + 294912;

  float* ws     = (float*)d_ws;
  float* Rv     = ws;                      // 4096
  float* mv     = ws + 4096;               // 4096
  float* colsum = ws + 8192;               // 49152
  float* diagv  = ws + 57344;              // 49152

  pack_w_kernel <<<dim3(576),     dim3(256),   0, stream>>>(Wq, Wk, Wqh, Wql, Wkh, Wkl);
  proj_mfma_kernel<<<dim3(6,32,2), dim3(256),  0, stream>>>(x, Wqh, Wql, Wkh, Wkl, bq, bk, Qs, Ks);
  root_kernel   <<<dim3(1024),    dim3(256),   0, stream>>>(x, Wr, br, mask, Rv, mv);
  scores_kernel <<<dim3(4,4,96),  dim3(16,16), 0, stream>>>(Qs, Ks, mv, d_region);
  pack_x_kernel <<<dim3(1536),    dim3(256),   0, stream>>>(x, xh, xl);
  colsum_kernel <<<dim3(2,96),    dim3(256),   0, stream>>>(d_region, colsum);
  buildM_kernel <<<dim3(24576),   dim3(256),   0, stream>>>(d_region, colsum, Rv, Mv);

  for (int step = 0; step < 8; ++step) {
    const int k0 = step * 64;
    gj_inv_kernel   <<<dim3(96),     dim3(64),    0, stream>>>(Mv, Invs, k0);
    gj_w_kernel     <<<dim3(4,96),   dim3(16,16), 0, stream>>>(Mv, Mp, Invs, k0);
    gj_update_kernel<<<dim3(4,4,96), dim3(16,16), 0, stream>>>(Mv, Mp, k0);
  }

  diag_d0_kernel<<<dim3(96),      dim3(512),   0, stream>>>(Mv, Rv, diagv, d0_region);
  loss_kernel   <<<dim3(1),       dim3(1024),  0, stream>>>(d0_region, roots, loss_ptr);
  finalize_d_kernel<<<dim3(8,8,96), dim3(64,4), 0, stream>>>(d_region, Mv, diagv);
  context_packed_kernel<<<dim3(6,4,88), dim3(256), 0, stream>>>(d_region, xh, xl, mv, ctx_region);
  context_mfma_kernel  <<<dim3(6,4,8),  dim3(256), 0, stream>>>(d_region, x, mv, ctx_region);
}